// Round 1
// baseline (167.934 us; speedup 1.0000x reference)
//
#include <hip/hip_runtime.h>

// out[b,i,h,w] = w1 * x[b,h,w-s1] * (w>=s1)  +  w2 * x[b,h,w+s2] * (w+s2<256)
//   s1 = (i+1)>>1, s2 = (i+2)>>1
// x: (2,1,256,256) f32; out: (2,256,256,256) f32 (128 MiB) -> write-BW bound.

__global__ __launch_bounds__(256) void ConvolutionalOverlap_kernel(
    const float* __restrict__ x,
    const float* __restrict__ w1p,
    const float* __restrict__ w2p,
    float* __restrict__ out,
    int total4)
{
    const float w1 = w1p[0];
    const float w2 = w2p[0];
    const int stride = gridDim.x * blockDim.x;

    for (int idx = blockIdx.x * blockDim.x + threadIdx.x; idx < total4;
         idx += stride) {
        // flat float4 index -> (b, i, h, w4); w = 4*w4 + j
        const int w4 = idx & 63;           // 64 float4 per row of 256
        const int h  = (idx >> 6)  & 255;
        const int i  = (idx >> 14) & 255;
        const int b  = idx >> 22;

        const int s1 = (i + 1) >> 1;       // left shift amount, 0..128
        const int s2 = (i + 2) >> 1;       // right shift amount, 1..128

        const float* __restrict__ row = x + (b << 16) + (h << 8);

        const int w0 = w4 << 2;
        float4 o;
        float* op = reinterpret_cast<float*>(&o);
        #pragma unroll
        for (int j = 0; j < 4; ++j) {
            const int w = w0 + j;
            float v = 0.0f;
            if (w >= s1)      v  = w1 * row[w - s1];   // idx1 in-bounds
            if (w + s2 < 256) v += w2 * row[w + s2];   // idx2 in-bounds
            op[j] = v;
        }
        reinterpret_cast<float4*>(out)[idx] = o;
    }
}

extern "C" void kernel_launch(void* const* d_in, const int* in_sizes, int n_in,
                              void* d_out, int out_size, void* d_ws, size_t ws_size,
                              hipStream_t stream) {
    const float* x  = (const float*)d_in[0];
    const float* w1 = (const float*)d_in[1];
    const float* w2 = (const float*)d_in[2];
    float* out = (float*)d_out;

    const int total4 = out_size / 4;   // 8,388,608 float4 stores
    const int block = 256;
    const int grid = 2048;             // 8 blocks/CU, grid-stride covers rest

    hipLaunchKernelGGL(ConvolutionalOverlap_kernel, dim3(grid), dim3(block), 0,
                       stream, x, w1, w2, out, total4);
}

// Round 2
// 156.451 us; speedup vs baseline: 1.0734x; 1.0734x over previous
//
#include <hip/hip_runtime.h>

// out[b,i,h,w] = w1 * x[b,0,h,w-s1] * (w-s1 >= 0)  +  w2 * x[b,0,h,w+s2] * (w+s2 < 256)
//   s1 = (i+1)>>1 in [0,128],  s2 = (i+2)>>1 in [1,128]
// x: (2,1,256,256) f32 (512 KB, cache-resident); out: (2,256,256,256) f32 (128 MiB).
// Pure write-BW-bound. Strategy: stage the 1 KB x-row in LDS extended with
// zero pads over [-128, 383] so the boundary masks become free (OOB taps read
// zero). One wave emits one full 256-float output row per iteration as
// coalesced float4 stores.

__global__ __launch_bounds__(256) void ConvolutionalOverlap_kernel(
    const float* __restrict__ x,
    const float* __restrict__ w1p,
    const float* __restrict__ w2p,
    float* __restrict__ out)
{
    // lds word a holds x-row index (a - 128); [0,128) and [384,512) are zero.
    __shared__ float lds[512];

    const int bid = blockIdx.x;        // 2048 blocks = b(2) * h(256) * ichunk(4)
    const int b   = bid >> 10;
    const int h   = (bid >> 2) & 255;
    const int ic  = bid & 3;           // which 64-wide i chunk
    const int t   = threadIdx.x;

    // Stage: zero pads + row (all 512 words covered exactly once).
    if (t < 128) lds[t] = 0.0f;        // [0,128)
    else         lds[256 + t] = 0.0f;  // [384,512)
    lds[128 + t] = x[(b << 16) + (h << 8) + t];
    __syncthreads();

    const float w1 = w1p[0];
    const float w2 = w2p[0];

    const int lane = t & 63;
    const int wv   = t >> 6;           // wave id 0..3
    const int w0   = lane << 2;        // this lane's 4 output columns

    #pragma unroll 4
    for (int it = 0; it < 16; ++it) {
        const int i  = (ic << 6) + (it << 2) + wv;   // output row (i dim)
        const int s1 = (i + 1) >> 1;
        const int s2 = (i + 2) >> 1;

        const int a1 = 128 - s1 + w0;  // lds index of tap1 for w = w0
        const int a2 = 128 + s2 + w0;  // lds index of tap2 for w = w0

        float4 o;
        o.x = w1 * lds[a1]     + w2 * lds[a2];
        o.y = w1 * lds[a1 + 1] + w2 * lds[a2 + 1];
        o.z = w1 * lds[a1 + 2] + w2 * lds[a2 + 2];
        o.w = w1 * lds[a1 + 3] + w2 * lds[a2 + 3];

        // out flat index: (b<<24) + (i<<16) + (h<<8) + w
        float4* dst = reinterpret_cast<float4*>(
            out + (b << 24) + (i << 16) + (h << 8) + w0);
        *dst = o;
    }
}

extern "C" void kernel_launch(void* const* d_in, const int* in_sizes, int n_in,
                              void* d_out, int out_size, void* d_ws, size_t ws_size,
                              hipStream_t stream) {
    const float* x  = (const float*)d_in[0];
    const float* w1 = (const float*)d_in[1];
    const float* w2 = (const float*)d_in[2];
    float* out = (float*)d_out;

    const int grid  = 2 * 256 * 4;   // (b, h, i-chunk)
    const int block = 256;

    hipLaunchKernelGGL(ConvolutionalOverlap_kernel, dim3(grid), dim3(block), 0,
                       stream, x, w1, w2, out);
}

// Round 3
// 143.287 us; speedup vs baseline: 1.1720x; 1.0919x over previous
//
#include <hip/hip_runtime.h>

// out[b,i,h,w] = w1 * x[b,0,h,w-s1] * (w-s1 >= 0) + w2 * x[b,0,h,w+s2] * (w+s2 < 256)
//   s1 = (i+1)>>1 in [0,128],  s2 = (i+2)>>1 in [1,128]
// x: (2,1,256,256) f32; out: (2,256,256,256) f32 (128 MiB) -> write-BW bound (~21 us).
//
// Strategy: build xpad[2][256][512] in d_ws (row = 128 zeros | x row | 128 zeros),
// then the masked gather becomes two unconditional unaligned vec4 loads per
// float4 output (shifts are block-uniform -> SGPRs, loads contiguous across
// lanes -> fully coalesced), plus one coalesced nontemporal float4 store.

typedef float v4f __attribute__((ext_vector_type(4)));

// Kernel 1: build padded x in workspace. 65536 float4 writes (1 MiB).
__global__ __launch_bounds__(256) void pad_kernel(
    const float* __restrict__ x, float* __restrict__ xpad)
{
    const int f = blockIdx.x * 256 + threadIdx.x;   // float4 index in xpad
    const int r = f >> 7;          // padded row 0..511  (b*256 + h)
    const int c = f & 127;         // float4 col within 512-float row

    v4f v;
    if (c < 32 || c >= 96) {
        v = (v4f){0.f, 0.f, 0.f, 0.f};
    } else {
        v = *reinterpret_cast<const v4f*>(x + (r << 8) + ((c - 32) << 2));
    }
    *reinterpret_cast<v4f*>(xpad + (f << 2)) = v;
}

// Kernel 2: 2048 blocks = b(2) x i(256) x hchunk(4); 256 threads; 16 iters.
__global__ __launch_bounds__(256) void ConvolutionalOverlap_kernel(
    const float* __restrict__ xpad,
    const float* __restrict__ w1p,
    const float* __restrict__ w2p,
    float* __restrict__ out)
{
    const int bid = blockIdx.x;
    const int b   = bid >> 10;
    const int i   = (bid >> 2) & 255;
    const int hc  = bid & 3;

    const float w1 = w1p[0];
    const float w2 = w2p[0];

    const int s1 = (i + 1) >> 1;       // block-uniform -> SGPR
    const int s2 = (i + 2) >> 1;

    const int t  = threadIdx.x;
    const int w4 = t & 63;             // float4 column
    const int hs = t >> 6;             // h sub-row 0..3 per iteration
    const int w0 = w4 << 2;

    // Base pointers for this block
    const float* __restrict__ padb = xpad + (b << 17);            // [256][512]
    float* __restrict__ outb = out + (b << 24) + (i << 16) + (hc << 14);

    #pragma unroll
    for (int it = 0; it < 16; ++it) {
        const int hl = (it << 2) + hs;             // local h 0..63
        const float* __restrict__ rowp = padb + (hl << 9) + ((hc << 6) << 9 >> 0) ;
        // NOTE: h = hc*64 + hl; recompute cleanly below to avoid confusion:
        const float* __restrict__ row = padb + (((hc << 6) + hl) << 9);

        const float* p1 = row + 128 + w0 - s1;     // tap1 (left shift)
        const float* p2 = row + 128 + w0 + s2;     // tap2 (right shift)

        v4f a, c;
        __builtin_memcpy(&a, p1, 16);              // unaligned dwordx4, 4B-align OK
        __builtin_memcpy(&c, p2, 16);

        v4f o = w1 * a + w2 * c;

        v4f* dst = reinterpret_cast<v4f*>(outb + (hl << 8) + w0);
        __builtin_nontemporal_store(o, dst);
        (void)rowp;
    }
}

extern "C" void kernel_launch(void* const* d_in, const int* in_sizes, int n_in,
                              void* d_out, int out_size, void* d_ws, size_t ws_size,
                              hipStream_t stream) {
    const float* x  = (const float*)d_in[0];
    const float* w1 = (const float*)d_in[1];
    const float* w2 = (const float*)d_in[2];
    float* out  = (float*)d_out;
    float* xpad = (float*)d_ws;      // needs 2*256*512*4 = 1 MiB

    hipLaunchKernelGGL(pad_kernel, dim3(256), dim3(256), 0, stream, x, xpad);
    hipLaunchKernelGGL(ConvolutionalOverlap_kernel, dim3(2048), dim3(256), 0,
                       stream, xpad, w1, w2, out);
}